// Round 1
// 101.019 us; speedup vs baseline: 1.0379x; 1.0379x over previous
//
#include <hip/hip_runtime.h>
#include <hip/hip_bf16.h>
#include <math.h>

// Problem constants (reference: B=32, P=256, D=64, T=4096, SCALE=1)
#define Bb 32
#define Pp 256
#define Dd 64
#define Tt 4096

typedef unsigned short ushort_t;
typedef __attribute__((ext_vector_type(8))) short bf16x8;   // 8 bf16 = 4 VGPRs
typedef __attribute__((ext_vector_type(4))) float f32x4;

#define TRIP_BYTES ((size_t)Bb * Pp * 64 * 16)   // 8,388,608
#define A_BF_BYTES ((size_t)Bb * Pp * Dd * 2)    // 1,048,576 (each of hi/lo)
#define B_BF_BYTES ((size_t)Tt * Dd * 2)         //   524,288 (each of hi/lo)
#define WS_NEED    (TRIP_BYTES + 2 * A_BF_BYTES + 2 * B_BF_BYTES)

// ---- DPP row-local shuffle on the VALU pipe (replaces DS-pipe ds_swizzle).
// Our butterfly domain is l16 (lanes within a 16-lane DPP row): quads == rows.
// ctrl: quad_perm xor1 = 0xB1, quad_perm xor2 = 0x4E,
//       row_half_mirror = 0x141 (cross-4 merge; 4-groups uniform after r1-r2),
//       row_mirror      = 0x140 (cross-8 merge; 8-groups uniform after r3).
template <int CTRL>
__device__ __forceinline__ float dppf(float x) {
  return __builtin_bit_cast(float,
      __builtin_amdgcn_update_dpp(0, __builtin_bit_cast(int, x), CTRL, 0xF, 0xF, true));
}

// R9-proven split-bf16 6-MFMA product (drops al*bl, ~2^-17 rel err)
__device__ __forceinline__ f32x4 mfma6(bf16x8 ah0, bf16x8 ah1, bf16x8 al0, bf16x8 al1,
                                       bf16x8 bh0, bf16x8 bh1, bf16x8 bl0, bf16x8 bl1) {
  f32x4 a = (f32x4)0.f;
  a = __builtin_amdgcn_mfma_f32_16x16x32_bf16(ah0, bh0, a, 0, 0, 0);
  a = __builtin_amdgcn_mfma_f32_16x16x32_bf16(ah1, bh1, a, 0, 0, 0);
  a = __builtin_amdgcn_mfma_f32_16x16x32_bf16(ah0, bl0, a, 0, 0, 0);
  a = __builtin_amdgcn_mfma_f32_16x16x32_bf16(al0, bh0, a, 0, 0, 0);
  a = __builtin_amdgcn_mfma_f32_16x16x32_bf16(ah1, bl1, a, 0, 0, 0);
  a = __builtin_amdgcn_mfma_f32_16x16x32_bf16(al1, bh1, a, 0, 0, 0);
  return a;
}

// =============== Phase 0: split-bf16 conversion of A and B ==================
__global__ __launch_bounds__(256) void k_conv(const float* __restrict__ data,
                                              const float* __restrict__ Wt,
                                              ushort_t* __restrict__ Ah, ushort_t* __restrict__ Al,
                                              ushort_t* __restrict__ Bh, ushort_t* __restrict__ Bl) {
  const int i  = blockIdx.x * 256 + threadIdx.x;
  const int NA = Bb * Pp * Dd;    // 524288
  const float x = (i < NA) ? data[i] : Wt[i - NA];
  const __hip_bfloat16 h = __float2bfloat16(x);
  const float hf = __bfloat162float(h);
  const __hip_bfloat16 l = __float2bfloat16(x - hf);
  if (i < NA) { Ah[i] = *(const ushort_t*)&h; Al[i] = *(const ushort_t*)&l; }
  else        { const int j = i - NA;
                Bh[j] = *(const ushort_t*)&h; Bl[j] = *(const ushort_t*)&l; }
}

// ==================== Phase 1: one-pass fused prefix-softmax ================
// R13: k_main was DS-pipe-bound (one LDS pipe/CU shared by 4 SIMDs; ~64% busy
// from 16 ds_read_b128 + ~60 shuffles per sg per wave, + 1.6M conflict cyc).
// Fix: (a) B-frags are sg-invariant -> hoisted to 64 VGPRs, loaded ONCE from
// global bf16 (coalesced dwordx4); LDS staging + __shared__ + bank conflicts
// deleted entirely. (b) The l16 butterflies (exact-max rounds, rescale,
// sum rounds) now use DPP row ops on the VALU pipe (4 pipes/CU) instead of
// DS shuffles. Only the 12 cross-quad scan shuffles (xor16/32) remain on DS.
// (c) A-frags double-buffered in registers: next sg's loads issue before the
// current sg's MFMA/softmax, hiding L1/L2 latency at 2 waves/SIMD.
// Numerics identical to R12 (proven): quad-exclusive prefix, batch softmax
// with exact per-lane max, per-wave exact M (argmax term exp(0)=1 -> S>=1).
__global__ __launch_bounds__(256, 2) void k_main(const ushort_t* __restrict__ Ah,
                                                 const ushort_t* __restrict__ Al,
                                                 const ushort_t* __restrict__ Bh,
                                                 const ushort_t* __restrict__ Bl,
                                                 const float* __restrict__ targets,
                                                 float4* __restrict__ triples) {
  const int tid  = threadIdx.x;
  const int wid  = tid >> 6;
  const int lane = tid & 63;
  const int quad = lane >> 4;
  const int l16  = lane & 15;
  const int b     = blockIdx.x >> 4;
  const int strip = blockIdx.x & 15;
  const int t0    = strip * 256;
  const int wstrip = strip * 4 + wid;           // 0..63 (this wave's t-subset id)

  // ---- B fragments for this wave's 64 t-columns: VGPR-resident for all sgs.
  // Global pattern per load: 16 rows x 16B at 128B row stride (full cachelines
  // across the 4 frags); total 8KB/wave from L2-resident Bh/Bl.
  bf16x8 vbh0[4], vbh1[4], vbl0[4], vbl1[4];
#pragma unroll
  for (int nt = 0; nt < 4; ++nt) {
    const size_t boff = (size_t)(t0 + wid * 64 + nt * 16 + l16) * Dd + quad * 8;
    vbh0[nt] = *(const bf16x8*)(Bh + boff);
    vbh1[nt] = *(const bf16x8*)(Bh + boff + 32);
    vbl0[nt] = *(const bf16x8*)(Bl + boff);
    vbl1[nt] = *(const bf16x8*)(Bl + boff + 32);
  }

  const ushort_t* arow_base = Ah + (size_t)b * Pp * Dd;
  const ushort_t* alow_base = Al + (size_t)b * Pp * Dd;
  float4* __restrict__ trb  = triples + (size_t)b * Pp * 64;

  float R[4];                                   // per-column running prefix
#pragma unroll
  for (int nt = 0; nt < 4; ++nt) R[nt] = 0.f;

  // prologue: A fragments + targets for sg=0
  const size_t aoff0 = (size_t)l16 * Dd + quad * 8;
  bf16x8 ah0 = *(const bf16x8*)(arow_base + aoff0);
  bf16x8 ah1 = *(const bf16x8*)(arow_base + aoff0 + 32);
  bf16x8 al0 = *(const bf16x8*)(alow_base + aoff0);
  bf16x8 al1 = *(const bf16x8*)(alow_base + aoff0 + 32);
  float4 tq  = *(const float4*)(targets + b * Pp + quad * 4);

#pragma unroll 1
  for (int sg = 0; sg < 16; ++sg) {
    // ---- prefetch next sg's A-frags (wraps at sg=15: harmless L1-hot reload)
    const int pn = ((sg + 1) & 15) * 16;
    const size_t an = (size_t)(pn + l16) * Dd + quad * 8;
    const bf16x8 nah0 = *(const bf16x8*)(arow_base + an);
    const bf16x8 nah1 = *(const bf16x8*)(arow_base + an + 32);
    const bf16x8 nal0 = *(const bf16x8*)(alow_base + an);
    const bf16x8 nal1 = *(const bf16x8*)(alow_base + an + 32);
    const float4 ntq  = *(const float4*)(targets + b * Pp + pn + quad * 4);

    float cc[4][4], av[4][4];
#pragma unroll
    for (int nt = 0; nt < 4; ++nt) {
      const f32x4 a = mfma6(ah0, ah1, al0, al1,
                            vbh0[nt], vbh1[nt], vbl0[nt], vbl1[nt]);
      float sc[4];
      { const float e = tq.x - a[0]; sc[0] = -0.5f * e * e; }
      { const float e = tq.y - a[1]; sc[1] = -0.5f * e * e; }
      { const float e = tq.z - a[2]; sc[2] = -0.5f * e * e; }
      { const float e = tq.w - a[3]; sc[3] = -0.5f * e * e; }

      // quad-exclusive prefix of column sums (R11-proven; cross-row -> DS)
      const float colsum = (sc[0] + sc[1]) + (sc[2] + sc[3]);
      const float x1 = __shfl_xor(colsum, 16, 64);
      const float x2 = __shfl_xor(colsum, 32, 64);
      const float x3 = __shfl_xor(x1, 32, 64);
      const float pre = (quad == 0) ? 0.f
                      : (quad == 1) ? x1
                      : (quad == 2) ? (x2 + x3)
                                    : (x1 + x2 + x3);
      const float base = R[nt] + pre;
      cc[nt][0] = base;
      cc[nt][1] = base + sc[0];
      cc[nt][2] = cc[nt][1] + sc[1];
      cc[nt][3] = cc[nt][2] + sc[2];
#pragma unroll
      for (int r = 0; r < 4; ++r) av[nt][r] = a[r];

      R[nt] += ((colsum + x1) + (x2 + x3));     // inclusive through this sg
    }

    // batch softmax over this lane's 4 columns, per p-row r (exact in-lane max)
    float mm[4], ss[4], vv[4];
#pragma unroll
    for (int r = 0; r < 4; ++r) {
      const float m01 = fmaxf(cc[0][r], cc[1][r]);
      const float m23 = fmaxf(cc[2][r], cc[3][r]);
      mm[r] = fmaxf(m01, m23);
      float s = 0.f, v = 0.f;
#pragma unroll
      for (int nt = 0; nt < 4; ++nt) {
        const float e = __expf(cc[nt][r] - mm[r]);
        s += e;
        v = fmaf(e, av[nt][r], v);
      }
      ss[r] = s; vv[r] = v;
    }

    // l16 butterfly on the VALU pipe via DPP: exact max rounds, single
    // rescale (==1 at the argmax lane -> S>=1, NaN-safe), plain-sum rounds.
    float M[4];
#pragma unroll
    for (int r = 0; r < 4; ++r) M[r] = mm[r];
#pragma unroll
    for (int r = 0; r < 4; ++r) M[r] = fmaxf(M[r], dppf<0xB1>(M[r]));   // xor1
#pragma unroll
    for (int r = 0; r < 4; ++r) M[r] = fmaxf(M[r], dppf<0x4E>(M[r]));   // xor2
#pragma unroll
    for (int r = 0; r < 4; ++r) M[r] = fmaxf(M[r], dppf<0x141>(M[r]));  // cross-4
#pragma unroll
    for (int r = 0; r < 4; ++r) M[r] = fmaxf(M[r], dppf<0x140>(M[r]));  // cross-8
#pragma unroll
    for (int r = 0; r < 4; ++r) {
      const float f = __expf(mm[r] - M[r]);
      ss[r] *= f; vv[r] *= f;
    }
#pragma unroll
    for (int r = 0; r < 4; ++r) { ss[r] += dppf<0xB1>(ss[r]);  vv[r] += dppf<0xB1>(vv[r]); }
#pragma unroll
    for (int r = 0; r < 4; ++r) { ss[r] += dppf<0x4E>(ss[r]);  vv[r] += dppf<0x4E>(vv[r]); }
#pragma unroll
    for (int r = 0; r < 4; ++r) { ss[r] += dppf<0x141>(ss[r]); vv[r] += dppf<0x141>(vv[r]); }
#pragma unroll
    for (int r = 0; r < 4; ++r) { ss[r] += dppf<0x140>(ss[r]); vv[r] += dppf<0x140>(vv[r]); }

    if (l16 == 0) {
#pragma unroll
      for (int r = 0; r < 4; ++r) {
        const int p = sg * 16 + quad * 4 + r;
        trb[p * 64 + wstrip] = make_float4(M[r], ss[r], vv[r], 0.f);
      }
    }

    ah0 = nah0; ah1 = nah1; al0 = nal0; al1 = nal1; tq = ntq;
  }
}

// ==================== Phase 2: cross-strip merge (R6-proven) ================
__global__ __launch_bounds__(256) void k_merge(const float4* __restrict__ ws,
                                               float* __restrict__ out) {
  const int gt   = blockIdx.x * 256 + threadIdx.x;
  const int bp   = gt >> 6;
  const int lane = gt & 63;
  const float4 o = ws[(size_t)bp * 64 + lane];
  const float m = o.x, s = o.y, v = o.z;
  float M = m;
#pragma unroll
  for (int off = 32; off; off >>= 1) M = fmaxf(M, __shfl_xor(M, off, 64));
  const float f = __expf(m - M);
  float S = f * s, V = f * v;
#pragma unroll
  for (int off = 32; off; off >>= 1) {
    S += __shfl_xor(S, off, 64);
    V += __shfl_xor(V, off, 64);
  }
  if (lane == 0) out[bp] = V / S;
}

// ============== Fallback (tiny ws): fused R1 structure + merge ==============
__global__ __launch_bounds__(256) void k_scan_fused(const float* __restrict__ data,
                                                    const float* __restrict__ targets,
                                                    const float* __restrict__ task_pool,
                                                    float4* __restrict__ ws) {
  const int b     = blockIdx.x >> 4;
  const int wid   = threadIdx.x >> 6;
  const int lane  = threadIdx.x & 63;
  const int chunk = ((blockIdx.x & 15) << 2) | wid;
  const int t     = (chunk << 6) | lane;
  float w[Dd];
#pragma unroll
  for (int d = 0; d < Dd; d += 4) {
    const float4 r = *(const float4*)(task_pool + (size_t)t * Dd + d);
    w[d] = r.x; w[d + 1] = r.y; w[d + 2] = r.z; w[d + 3] = r.w;
  }
  const float* drow = data + (size_t)b * (Pp * Dd);
  const float* tgt  = targets + b * Pp;
  float4* wsb       = ws + (size_t)b * (Pp * 64);
  float c = 0.f;
  for (int p = 0; p < Pp; ++p) {
    float a0 = 0.f, a1 = 0.f, a2 = 0.f, a3 = 0.f;
    const float* r = drow + p * Dd;
#pragma unroll
    for (int d = 0; d < Dd; d += 4) {
      a0 = fmaf(r[d], w[d], a0);         a1 = fmaf(r[d + 1], w[d + 1], a1);
      a2 = fmaf(r[d + 2], w[d + 2], a2); a3 = fmaf(r[d + 3], w[d + 3], a3);
    }
    const float pred = (a0 + a1) + (a2 + a3);
    float m = c;
#pragma unroll
    for (int off = 32; off; off >>= 1) m = fmaxf(m, __shfl_xor(m, off, 64));
    const float e = __expf(c - m);
    float s = e, v = e * pred;
#pragma unroll
    for (int off = 32; off; off >>= 1) {
      s += __shfl_xor(s, off, 64);
      v += __shfl_xor(v, off, 64);
    }
    if (lane == 0) wsb[p * 64 + chunk] = make_float4(m, s, v, 0.f);
    const float err = tgt[p] - pred;
    c = fmaf(-0.5f * err, err, c);
  }
}

extern "C" void kernel_launch(void* const* d_in, const int* in_sizes, int n_in,
                              void* d_out, int out_size, void* d_ws, size_t ws_size,
                              hipStream_t stream) {
  const float* data      = (const float*)d_in[0];
  const float* targets   = (const float*)d_in[1];
  const float* task_pool = (const float*)d_in[2];
  float* out = (float*)d_out;

  if (ws_size >= WS_NEED) {
    float4*   trips = (float4*)d_ws;
    char*     cb    = (char*)d_ws + TRIP_BYTES;
    ushort_t* Ah    = (ushort_t*)cb;
    ushort_t* Al    = (ushort_t*)(cb + A_BF_BYTES);
    ushort_t* Bh    = (ushort_t*)(cb + 2 * A_BF_BYTES);
    ushort_t* Bl    = (ushort_t*)(cb + 2 * A_BF_BYTES + B_BF_BYTES);
    k_conv <<<dim3((Bb * Pp * Dd + Tt * Dd) / 256), dim3(256), 0, stream>>>(
        data, task_pool, Ah, Al, Bh, Bl);
    k_main <<<dim3(Bb * 16), dim3(256), 0, stream>>>(Ah, Al, Bh, Bl, targets, trips);
    k_merge<<<dim3((Bb * Pp * 64) / 256), dim3(256), 0, stream>>>(trips, out);
  } else {
    float4* triples = (float4*)d_ws;   // 8.4 MB
    k_scan_fused<<<dim3(512), dim3(256), 0, stream>>>(data, targets, task_pool, triples);
    k_merge<<<dim3((Bb * Pp * 64) / 256), dim3(256), 0, stream>>>(triples, out);
  }
}